// Round 10
// baseline (1354.758 us; speedup 1.0000x reference)
//
#include <hip/hip_runtime.h>
#include <hip/hip_bf16.h>

typedef __hip_bfloat16 bf16;
typedef __hip_bfloat162 bf162;

#define U_N   100000
#define B_N   50000
#define N_TOT 150000
#define NE_UB 800000
#define NE_BB 600000
#define NP    400000
#define DU    64
#define DB    128
#define HD    128

__device__ __forceinline__ float b2f(bf16 v) { return __bfloat162float(v); }
__device__ __forceinline__ float2 ldb2(const bf16* row, int lane) {
    bf162 v = ((const bf162*)row)[lane];
    return make_float2(b2f(v.x), b2f(v.y));
}
__device__ __forceinline__ void stb2(bf16* row, int lane, float2 v) {
    bf162 o;
    o.x = __float2bfloat16(v.x);
    o.y = __float2bfloat16(v.y);
    ((bf162*)row)[lane] = o;
}

// ---------------- dense blocks (f32 compute; f32 and/or bf16 outputs) ----------------

// 16 rows per 128-thread block; 1 weight load : 16 FMA per k
template<int K>
__global__ void k_init_gemm(const float* __restrict__ x, const float* __restrict__ W,
                            const float* __restrict__ bias,
                            float* outf, bf16* out16, int nrows) {
    __shared__ float row[16][K];
    const int c  = threadIdx.x;
    const int r0 = blockIdx.x * 16;
    for (int i = threadIdx.x; i < 16 * K; i += 128) {
        int rr = i / K, kk = i % K;
        int r = r0 + rr;
        row[rr][kk] = (r < nrows) ? x[(size_t)r * K + kk] : 0.0f;
    }
    __syncthreads();
    float acc[16];
#pragma unroll
    for (int i = 0; i < 16; i++) acc[i] = 0.0f;
    for (int k = 0; k < K; k++) {
        float w = W[k * HD + c];
#pragma unroll
        for (int i = 0; i < 16; i++) acc[i] = fmaf(row[i][k], w, acc[i]);
    }
    float bv = bias[c];
#pragma unroll
    for (int i = 0; i < 16; i++) {
        int r = r0 + i;
        if (r < nrows) {
            float v = acc[i] + bv;
            if (outf)  outf[(size_t)r * HD + c] = v;
            if (out16) out16[(size_t)r * HD + c] = __float2bfloat16(v);
        }
    }
}

// ---------------- CSR build: count -> scan -> fill ----------------

__global__ void k_cnt_ub(const int* __restrict__ us, const int* __restrict__ ud,
                         int* __restrict__ cnt) {
    int e = blockIdx.x * blockDim.x + threadIdx.x;
    if (e < NE_UB) {
        atomicAdd(&cnt[us[e]], 1);
        atomicAdd(&cnt[U_N + ud[e]], 1);
    }
}

__global__ void k_cnt_bb(const int* __restrict__ bd, int* __restrict__ cnt) {
    int e = blockIdx.x * blockDim.x + threadIdx.x;
    if (e < NE_BB) atomicAdd(&cnt[bd[e]], 1);
}

__global__ void k_dinv(const int* __restrict__ cnt, float* __restrict__ dinv) {
    int i = blockIdx.x * blockDim.x + threadIdx.x;
    if (i < N_TOT) {
        int d = cnt[i];
        dinv[i] = (d > 0) ? 1.0f / sqrtf((float)d) : 0.0f;
    }
}

__global__ void k_scan1(const int* __restrict__ cnt, int* __restrict__ rs,
                        int* __restrict__ bsum, int n) {
    __shared__ int ts[256];
    const int t = threadIdx.x;
    const int base = blockIdx.x * 1024 + t * 4;
    int v0 = (base + 0 < n) ? cnt[base + 0] : 0;
    int v1 = (base + 1 < n) ? cnt[base + 1] : 0;
    int v2 = (base + 2 < n) ? cnt[base + 2] : 0;
    int v3 = (base + 3 < n) ? cnt[base + 3] : 0;
    int local = v0 + v1 + v2 + v3;
    ts[t] = local;
    __syncthreads();
    for (int off = 1; off < 256; off <<= 1) {
        int x = (t >= off) ? ts[t - off] : 0;
        __syncthreads();
        ts[t] += x;
        __syncthreads();
    }
    int ex = ts[t] - local;
    if (base + 0 < n) rs[base + 0] = ex;
    if (base + 1 < n) rs[base + 1] = ex + v0;
    if (base + 2 < n) rs[base + 2] = ex + v0 + v1;
    if (base + 3 < n) rs[base + 3] = ex + v0 + v1 + v2;
    if (t == 0) bsum[blockIdx.x] = ts[255];
}

__global__ void k_scan2(int* __restrict__ bsum, int nb) {
    __shared__ int ts[256];
    const int t = threadIdx.x;
    const int base = t * 4;
    int v0 = (base + 0 < nb) ? bsum[base + 0] : 0;
    int v1 = (base + 1 < nb) ? bsum[base + 1] : 0;
    int v2 = (base + 2 < nb) ? bsum[base + 2] : 0;
    int v3 = (base + 3 < nb) ? bsum[base + 3] : 0;
    int local = v0 + v1 + v2 + v3;
    ts[t] = local;
    __syncthreads();
    for (int off = 1; off < 256; off <<= 1) {
        int x = (t >= off) ? ts[t - off] : 0;
        __syncthreads();
        ts[t] += x;
        __syncthreads();
    }
    int ex = ts[t] - local;
    if (base + 0 < nb) bsum[base + 0] = ex;
    if (base + 1 < nb) bsum[base + 1] = ex + v0;
    if (base + 2 < nb) bsum[base + 2] = ex + v0 + v1;
    if (base + 3 < nb) bsum[base + 3] = ex + v0 + v1 + v2;
}

__global__ void k_scan3(int* __restrict__ rs, const int* __restrict__ bsum, int n) {
    int i = blockIdx.x * blockDim.x + threadIdx.x;
    if (i < n) rs[i] += bsum[i >> 10];
}

__global__ void k_fill_ub(const int* __restrict__ us, const int* __restrict__ ud,
                          int* __restrict__ rs, int* __restrict__ eidx) {
    int e = blockIdx.x * blockDim.x + threadIdx.x;
    if (e < NE_UB) {
        int u = us[e];
        int b = U_N + ud[e];
        int pu = atomicAdd(&rs[u], 1);
        eidx[pu] = b;
        int pb = atomicAdd(&rs[b], 1);
        eidx[pb] = u;
    }
}

__global__ void k_fill_bb(const int* __restrict__ bs, const int* __restrict__ bd,
                          int* __restrict__ rs, int* __restrict__ eidx) {
    int e = blockIdx.x * blockDim.x + threadIdx.x;
    if (e < NE_BB) {
        int p = atomicAdd(&rs[bd[e]], 1);
        eidx[p] = bs[e];
    }
}

// ---------------- pull-mode propagation (bf16 tables, f32 accumulate) ----------------

__global__ void k_gather1(const int* __restrict__ rs, const int* __restrict__ eidx,
                          const float* __restrict__ dinv,
                          const bf16* __restrict__ x016, bf16* __restrict__ x116) {
    int w    = (blockIdx.x * blockDim.x + threadIdx.x) >> 6;
    int lane = threadIdx.x & 63;
    if (w >= N_TOT) return;
    int s = (w == 0) ? 0 : rs[w - 1];
    int e = rs[w];
    s = __builtin_amdgcn_readfirstlane(s);
    e = __builtin_amdgcn_readfirstlane(e);
    float nd = dinv[w];
    float2 acc = make_float2(0.0f, 0.0f);
    for (int j = s; j < e; ++j) {
        int nb = eidx[j];
        float wgt = nd * dinv[nb];
        float2 v = ldb2(x016 + (size_t)nb * HD, lane);
        acc.x = fmaf(v.x, wgt, acc.x);
        acc.y = fmaf(v.y, wgt, acc.y);
    }
    stb2(x116 + (size_t)w * HD, lane, acc);
}

__global__ void k_gather2(const int* __restrict__ rs, const int* __restrict__ eidx,
                          const float* __restrict__ dinv,
                          const bf16* __restrict__ x016, const bf16* __restrict__ x116,
                          bf16* __restrict__ xf16) {
    int w    = (blockIdx.x * blockDim.x + threadIdx.x) >> 6;
    int lane = threadIdx.x & 63;
    if (w >= N_TOT) return;
    int s = (w == 0) ? 0 : rs[w - 1];
    int e = rs[w];
    s = __builtin_amdgcn_readfirstlane(s);
    e = __builtin_amdgcn_readfirstlane(e);
    float nd = dinv[w];
    float2 acc = make_float2(0.0f, 0.0f);
    for (int j = s; j < e; ++j) {
        int nb = eidx[j];
        float wgt = nd * dinv[nb];
        float2 v = ldb2(x116 + (size_t)nb * HD, lane);
        acc.x = fmaf(v.x, wgt, acc.x);
        acc.y = fmaf(v.y, wgt, acc.y);
    }
    float2 a = ldb2(x016 + (size_t)w * HD, lane);
    float2 b = ldb2(x116 + (size_t)w * HD, lane);
    acc.x = (acc.x + a.x + b.x) * (1.0f / 3.0f);
    acc.y = (acc.y + a.y + b.y) * (1.0f / 3.0f);
    stb2(xf16 + (size_t)w * HD, lane, acc);
}

__global__ void k_gather_bb(const int* __restrict__ rs, const int* __restrict__ eidx,
                            const bf16* __restrict__ h16, float* __restrict__ agg) {
    int w    = (blockIdx.x * blockDim.x + threadIdx.x) >> 6;
    int lane = threadIdx.x & 63;
    if (w >= B_N) return;
    int s = (w == 0) ? 0 : rs[w - 1];
    int e = rs[w];
    s = __builtin_amdgcn_readfirstlane(s);
    e = __builtin_amdgcn_readfirstlane(e);
    float2 acc = make_float2(0.0f, 0.0f);
    for (int j = s; j < e; ++j) {
        int nb = eidx[j];
        float2 v = ldb2(h16 + (size_t)nb * HD, lane);
        acc.x += v.x;
        acc.y += v.y;
    }
    float inv = 1.0f / fmaxf((float)(e - s), 1.0f);
    acc.x *= inv;
    acc.y *= inv;
    ((float2*)(agg + (size_t)w * HD))[lane] = acc;
}

// hout = relu(agg@Wl + bl + h@Wr); 32 rows/block (2 loads : 64 FMA per k).
// In-place safe: rows staged in LDS behind barrier; blocks never share rows.
__global__ void k_glayer(const float* __restrict__ agg, const float* __restrict__ h,
                         const float* __restrict__ Wl, const float* __restrict__ bl,
                         const float* __restrict__ Wr,
                         float* outf, bf16* out16) {
    __shared__ float sa[32][HD];
    __shared__ float sh[32][HD];
    const int c  = threadIdx.x;
    const int r0 = blockIdx.x * 32;
#pragma unroll
    for (int i = 0; i < 32; i++) {
        int r = r0 + i;
        sa[i][c] = (r < B_N) ? agg[(size_t)r * HD + c] : 0.0f;
        sh[i][c] = (r < B_N) ? h[(size_t)r * HD + c] : 0.0f;
    }
    __syncthreads();
    float acc[32];
#pragma unroll
    for (int i = 0; i < 32; i++) acc[i] = 0.0f;
    for (int k = 0; k < HD; k++) {
        float wl = Wl[k * HD + c];
        float wr = Wr[k * HD + c];
#pragma unroll
        for (int i = 0; i < 32; i++) {
            acc[i] = fmaf(sa[i][k], wl, acc[i]);
            acc[i] = fmaf(sh[i][k], wr, acc[i]);
        }
    }
    float bv = bl[c];
#pragma unroll
    for (int i = 0; i < 32; i++) {
        int r = r0 + i;
        if (r < B_N) {
            float v = fmaxf(acc[i] + bv, 0.0f);
            if (outf)  outf[(size_t)r * HD + c] = v;
            if (out16) out16[(size_t)r * HD + c] = __float2bfloat16(v);
        }
    }
}

// attention fusion head, 16 rows per 128-thread block (1 load : 16 FMA per k)
__global__ void k_fuse(const bf16* __restrict__ collab16, const bf16* __restrict__ content16,
                       const float* __restrict__ Wf1, const float* __restrict__ bf1v,
                       const float* __restrict__ Wf2, const float* __restrict__ bf2v,
                       bf16* __restrict__ fused16) {
    const int R = 16;
    __shared__ float sc[R][HD];
    __shared__ float sh[R][HD];
    __shared__ float part[2][R][2];
    __shared__ float attn[R][2];
    const int c  = threadIdx.x;
    const int r0 = blockIdx.x * R;
#pragma unroll
    for (int i = 0; i < R; i++) {
        int r = r0 + i;
        sc[i][c] = (r < B_N) ? b2f(collab16[(size_t)r * HD + c]) : 0.0f;
        sh[i][c] = (r < B_N) ? b2f(content16[(size_t)r * HD + c]) : 0.0f;
    }
    __syncthreads();
    float t[R];
#pragma unroll
    for (int i = 0; i < R; i++) t[i] = 0.0f;
    for (int k = 0; k < HD; k++) {
        float w = Wf1[k * HD + c];
#pragma unroll
        for (int i = 0; i < R; i++) t[i] = fmaf(sc[i][k], w, t[i]);
    }
    for (int k = 0; k < HD; k++) {
        float w = Wf1[(size_t)(HD + k) * HD + c];
#pragma unroll
        for (int i = 0; i < R; i++) t[i] = fmaf(sh[i][k], w, t[i]);
    }
    float b1  = bf1v[c];
    float w20 = Wf2[c * 2 + 0];
    float w21 = Wf2[c * 2 + 1];
    float p0[R], p1[R];
#pragma unroll
    for (int i = 0; i < R; i++) {
        float tv = fmaxf(t[i] + b1, 0.0f);
        p0[i] = tv * w20;
        p1[i] = tv * w21;
    }
#pragma unroll
    for (int i = 0; i < R; i++) {
        for (int off = 32; off > 0; off >>= 1) {
            p0[i] += __shfl_down(p0[i], off, 64);
            p1[i] += __shfl_down(p1[i], off, 64);
        }
    }
    int wv   = threadIdx.x >> 6;
    int lane = threadIdx.x & 63;
    if (lane == 0) {
#pragma unroll
        for (int i = 0; i < R; i++) { part[wv][i][0] = p0[i]; part[wv][i][1] = p1[i]; }
    }
    __syncthreads();
    if (threadIdx.x < R) {
        int i = threadIdx.x;
        float s0 = part[0][i][0] + part[1][i][0] + bf2v[0];
        float s1 = part[0][i][1] + part[1][i][1] + bf2v[1];
        float m  = fmaxf(s0, s1);
        float e0 = expf(s0 - m), e1 = expf(s1 - m);
        float inv = 1.0f / (e0 + e1);
        attn[i][0] = e0 * inv;
        attn[i][1] = e1 * inv;
    }
    __syncthreads();
#pragma unroll
    for (int i = 0; i < R; i++) {
        int r = r0 + i;
        if (r < B_N) {
            float v = attn[i][0] * sc[i][c] + attn[i][1] * sh[i][c];
            fused16[(size_t)r * HD + c] = __float2bfloat16(v);
        }
    }
}

// one wave per prediction: dot(uemb16[pu], fused16[pb]); f32 out
__global__ void k_score(const int* __restrict__ pu, const int* __restrict__ pb,
                        const bf16* __restrict__ uemb16, const bf16* __restrict__ fused16,
                        float* __restrict__ out) {
    int wid  = (blockIdx.x * blockDim.x + threadIdx.x) >> 6;
    int lane = threadIdx.x & 63;
    if (wid >= NP) return;
    int u = pu[wid];
    int b = pb[wid];
    float2 a = ldb2(uemb16 + (size_t)u * HD, lane);
    float2 f = ldb2(fused16 + (size_t)b * HD, lane);
    float s = a.x * f.x + a.y * f.y;
    for (int off = 32; off > 0; off >>= 1) s += __shfl_down(s, off, 64);
    if (lane == 0) out[wid] = s;
}

extern "C" void kernel_launch(void* const* d_in, const int* in_sizes, int n_in,
                              void* d_out, int out_size, void* d_ws, size_t ws_size,
                              hipStream_t stream) {
    const float* user_x = (const float*)d_in[0];
    const float* book_x = (const float*)d_in[1];
    const int*   ub_src = (const int*)d_in[2];
    const int*   ub_dst = (const int*)d_in[3];
    const int*   bb_src = (const int*)d_in[4];
    const int*   bb_dst = (const int*)d_in[5];
    const int*   pred_u = (const int*)d_in[6];
    const int*   pred_b = (const int*)d_in[7];
    const float* Wu   = (const float*)d_in[8];
    const float* bu   = (const float*)d_in[9];
    const float* Wub  = (const float*)d_in[10];
    const float* bub  = (const float*)d_in[11];
    const float* Wbb  = (const float*)d_in[12];
    const float* bbb  = (const float*)d_in[13];
    const float* Wl1  = (const float*)d_in[14];
    const float* bl1  = (const float*)d_in[15];
    const float* Wr1  = (const float*)d_in[16];
    const float* Wl2  = (const float*)d_in[17];
    const float* bl2  = (const float*)d_in[18];
    const float* Wr2  = (const float*)d_in[19];
    const float* Wf1  = (const float*)d_in[20];
    const float* bf1v = (const float*)d_in[21];
    const float* Wf2  = (const float*)d_in[22];
    const float* bf2v = (const float*)d_in[23];
    float* out = (float*)d_out;

    // ---- workspace layout: 30.96M words = 123.84 MB (same as passing R9) ----
    float* ws = (float*)d_ws;
    const size_t need = 30960000ull * sizeof(float);
    if (ws_size < need) return;

    float* dinv    = ws;
    int*   cnt_ub  = (int*)(ws + 150000);
    int*   rs_ub   = (int*)(ws + 300000);
    int*   cnt_bb  = (int*)(ws + 450000);
    int*   rs_bb   = (int*)(ws + 500000);
    int*   bsum    = (int*)(ws + 550000);
    int*   eidx    = (int*)(ws + 560000);
    bf16*  X016    = (bf16*)(ws + 2160000);      // [2160000, 11760000)
    bf16*  X1_16   = (bf16*)(ws + 11760000);     // [11760000, 21360000)
    bf16*  XF16    = (bf16*)(ws + 21360000);     // [21360000, 30960000)
    float* hf        = ws + 2160000;             // [2160000, 8560000)
    bf16*  h16       = (bf16*)(ws + 8560000);    // [8560000, 11760000)
    float* aggf      = ws + 11760000;            // [11760000, 18160000)
    bf16*  content16 = h16;
    bf16*  fused16   = (bf16*)(ws + 11760000);
    bf16*  uemb16    = XF16;
    bf16*  collab16  = XF16 + (size_t)U_N * HD;

    hipMemsetAsync(ws + 150000, 0, 350000 * sizeof(float), stream);

    // x0 -> X016 (bf16)
    k_init_gemm<DU><<<(U_N + 15) / 16, 128, 0, stream>>>(
        user_x, Wu, bu, (float*)nullptr, X016, U_N);
    k_init_gemm<DB><<<(B_N + 15) / 16, 128, 0, stream>>>(
        book_x, Wub, bub, (float*)nullptr, X016 + (size_t)U_N * HD, B_N);

    // ---- CSR build (ub graph, bidirectional) ----
    k_cnt_ub<<<(NE_UB + 255) / 256, 256, 0, stream>>>(ub_src, ub_dst, cnt_ub);
    k_cnt_bb<<<(NE_BB + 255) / 256, 256, 0, stream>>>(bb_dst, cnt_bb);
    k_dinv<<<(N_TOT + 255) / 256, 256, 0, stream>>>(cnt_ub, dinv);
    {
        int nb = (N_TOT + 1023) / 1024;
        k_scan1<<<nb, 256, 0, stream>>>(cnt_ub, rs_ub, bsum, N_TOT);
        k_scan2<<<1, 256, 0, stream>>>(bsum, nb);
        k_scan3<<<(N_TOT + 255) / 256, 256, 0, stream>>>(rs_ub, bsum, N_TOT);
    }
    k_fill_ub<<<(NE_UB + 255) / 256, 256, 0, stream>>>(ub_src, ub_dst, rs_ub, eidx);

    // ---- LightGCN propagation ----
    k_gather1<<<(N_TOT + 3) / 4, 256, 0, stream>>>(rs_ub, eidx, dinv, X016, X1_16);
    k_gather2<<<(N_TOT + 3) / 4, 256, 0, stream>>>(rs_ub, eidx, dinv, X016, X1_16, XF16);

    // ---- CSR build (bb graph) ----
    {
        int nb = (B_N + 1023) / 1024;
        k_scan1<<<nb, 256, 0, stream>>>(cnt_bb, rs_bb, bsum, B_N);
        k_scan2<<<1, 256, 0, stream>>>(bsum, nb);
        k_scan3<<<(B_N + 255) / 256, 256, 0, stream>>>(rs_bb, bsum, B_N);
    }
    k_fill_bb<<<(NE_BB + 255) / 256, 256, 0, stream>>>(bb_src, bb_dst, rs_bb, eidx);

    // ---- content network ----
    k_init_gemm<DB><<<(B_N + 15) / 16, 128, 0, stream>>>(book_x, Wbb, bbb, hf, h16, B_N);
    k_gather_bb<<<(B_N + 3) / 4, 256, 0, stream>>>(rs_bb, eidx, h16, aggf);
    k_glayer<<<(B_N + 31) / 32, 128, 0, stream>>>(aggf, hf, Wl1, bl1, Wr1, hf, h16);
    k_gather_bb<<<(B_N + 3) / 4, 256, 0, stream>>>(rs_bb, eidx, h16, aggf);
    k_glayer<<<(B_N + 31) / 32, 128, 0, stream>>>(aggf, hf, Wl2, bl2, Wr2,
                                                  (float*)nullptr, content16);

    // ---- fusion + scores ----
    k_fuse<<<(B_N + 15) / 16, 128, 0, stream>>>(collab16, content16,
                                                Wf1, bf1v, Wf2, bf2v, fused16);
    k_score<<<NP / 4, 256, 0, stream>>>(pred_u, pred_b, uemb16, fused16, out);
}

// Round 11
// 1230.707 us; speedup vs baseline: 1.1008x; 1.1008x over previous
//
#include <hip/hip_runtime.h>
#include <hip/hip_bf16.h>

typedef __hip_bfloat16 bf16;
typedef __hip_bfloat162 bf162;

#define U_N   100000
#define B_N   50000
#define N_TOT 150000
#define NE_UB 800000
#define NE_BB 600000
#define NP    400000
#define DU    64
#define DB    128
#define HD    128

__device__ __forceinline__ float b2f(bf16 v) { return __bfloat162float(v); }
__device__ __forceinline__ float2 ldb2(const bf16* row, int lane) {
    bf162 v = ((const bf162*)row)[lane];
    return make_float2(b2f(v.x), b2f(v.y));
}
__device__ __forceinline__ void stb2(bf16* row, int lane, float2 v) {
    bf162 o;
    o.x = __float2bfloat16(v.x);
    o.y = __float2bfloat16(v.y);
    ((bf162*)row)[lane] = o;
}

// ---------------- dense blocks (f32 compute; f32 and/or bf16 outputs) ----------------
// __launch_bounds__(128): without it hipcc budgets VGPRs for 1024-thread blocks
// and SPILLS the accumulator arrays to scratch (R10: VGPR_Count=40 with acc[32],
// VALUBusy 13.8% -> 177us). With it, 256 VGPR/thread budget, acc stays resident.

// 16 rows per 128-thread block; 1 weight load : 16 FMA per k
template<int K>
__global__ __launch_bounds__(128)
void k_init_gemm(const float* __restrict__ x, const float* __restrict__ W,
                 const float* __restrict__ bias,
                 float* outf, bf16* out16, int nrows) {
    __shared__ float row[16][K];
    const int c  = threadIdx.x;
    const int r0 = blockIdx.x * 16;
    for (int i = threadIdx.x; i < 16 * K; i += 128) {
        int rr = i / K, kk = i % K;
        int r = r0 + rr;
        row[rr][kk] = (r < nrows) ? x[(size_t)r * K + kk] : 0.0f;
    }
    __syncthreads();
    float acc[16];
#pragma unroll
    for (int i = 0; i < 16; i++) acc[i] = 0.0f;
    for (int k = 0; k < K; k++) {
        float w = W[k * HD + c];
#pragma unroll
        for (int i = 0; i < 16; i++) acc[i] = fmaf(row[i][k], w, acc[i]);
    }
    float bv = bias[c];
#pragma unroll
    for (int i = 0; i < 16; i++) {
        int r = r0 + i;
        if (r < nrows) {
            float v = acc[i] + bv;
            if (outf)  outf[(size_t)r * HD + c] = v;
            if (out16) out16[(size_t)r * HD + c] = __float2bfloat16(v);
        }
    }
}

// ---------------- CSR build: count -> scan -> fill ----------------

__global__ void k_cnt_ub(const int* __restrict__ us, const int* __restrict__ ud,
                         int* __restrict__ cnt) {
    int e = blockIdx.x * blockDim.x + threadIdx.x;
    if (e < NE_UB) {
        atomicAdd(&cnt[us[e]], 1);
        atomicAdd(&cnt[U_N + ud[e]], 1);
    }
}

__global__ void k_cnt_bb(const int* __restrict__ bd, int* __restrict__ cnt) {
    int e = blockIdx.x * blockDim.x + threadIdx.x;
    if (e < NE_BB) atomicAdd(&cnt[bd[e]], 1);
}

__global__ void k_dinv(const int* __restrict__ cnt, float* __restrict__ dinv) {
    int i = blockIdx.x * blockDim.x + threadIdx.x;
    if (i < N_TOT) {
        int d = cnt[i];
        dinv[i] = (d > 0) ? 1.0f / sqrtf((float)d) : 0.0f;
    }
}

__global__ void k_scan1(const int* __restrict__ cnt, int* __restrict__ rs,
                        int* __restrict__ bsum, int n) {
    __shared__ int ts[256];
    const int t = threadIdx.x;
    const int base = blockIdx.x * 1024 + t * 4;
    int v0 = (base + 0 < n) ? cnt[base + 0] : 0;
    int v1 = (base + 1 < n) ? cnt[base + 1] : 0;
    int v2 = (base + 2 < n) ? cnt[base + 2] : 0;
    int v3 = (base + 3 < n) ? cnt[base + 3] : 0;
    int local = v0 + v1 + v2 + v3;
    ts[t] = local;
    __syncthreads();
    for (int off = 1; off < 256; off <<= 1) {
        int x = (t >= off) ? ts[t - off] : 0;
        __syncthreads();
        ts[t] += x;
        __syncthreads();
    }
    int ex = ts[t] - local;
    if (base + 0 < n) rs[base + 0] = ex;
    if (base + 1 < n) rs[base + 1] = ex + v0;
    if (base + 2 < n) rs[base + 2] = ex + v0 + v1;
    if (base + 3 < n) rs[base + 3] = ex + v0 + v1 + v2;
    if (t == 0) bsum[blockIdx.x] = ts[255];
}

__global__ void k_scan2(int* __restrict__ bsum, int nb) {
    __shared__ int ts[256];
    const int t = threadIdx.x;
    const int base = t * 4;
    int v0 = (base + 0 < nb) ? bsum[base + 0] : 0;
    int v1 = (base + 1 < nb) ? bsum[base + 1] : 0;
    int v2 = (base + 2 < nb) ? bsum[base + 2] : 0;
    int v3 = (base + 3 < nb) ? bsum[base + 3] : 0;
    int local = v0 + v1 + v2 + v3;
    ts[t] = local;
    __syncthreads();
    for (int off = 1; off < 256; off <<= 1) {
        int x = (t >= off) ? ts[t - off] : 0;
        __syncthreads();
        ts[t] += x;
        __syncthreads();
    }
    int ex = ts[t] - local;
    if (base + 0 < nb) bsum[base + 0] = ex;
    if (base + 1 < nb) bsum[base + 1] = ex + v0;
    if (base + 2 < nb) bsum[base + 2] = ex + v0 + v1;
    if (base + 3 < nb) bsum[base + 3] = ex + v0 + v1 + v2;
}

__global__ void k_scan3(int* __restrict__ rs, const int* __restrict__ bsum, int n) {
    int i = blockIdx.x * blockDim.x + threadIdx.x;
    if (i < n) rs[i] += bsum[i >> 10];
}

__global__ void k_fill_ub(const int* __restrict__ us, const int* __restrict__ ud,
                          int* __restrict__ rs, int* __restrict__ eidx) {
    int e = blockIdx.x * blockDim.x + threadIdx.x;
    if (e < NE_UB) {
        int u = us[e];
        int b = U_N + ud[e];
        int pu = atomicAdd(&rs[u], 1);
        eidx[pu] = b;
        int pb = atomicAdd(&rs[b], 1);
        eidx[pb] = u;
    }
}

__global__ void k_fill_bb(const int* __restrict__ bs, const int* __restrict__ bd,
                          int* __restrict__ rs, int* __restrict__ eidx) {
    int e = blockIdx.x * blockDim.x + threadIdx.x;
    if (e < NE_BB) {
        int p = atomicAdd(&rs[bd[e]], 1);
        eidx[p] = bs[e];
    }
}

// ---------------- pull-mode propagation (bf16 tables, f32 accumulate) ----------------

__global__ void k_gather1(const int* __restrict__ rs, const int* __restrict__ eidx,
                          const float* __restrict__ dinv,
                          const bf16* __restrict__ x016, bf16* __restrict__ x116) {
    int w    = (blockIdx.x * blockDim.x + threadIdx.x) >> 6;
    int lane = threadIdx.x & 63;
    if (w >= N_TOT) return;
    int s = (w == 0) ? 0 : rs[w - 1];
    int e = rs[w];
    s = __builtin_amdgcn_readfirstlane(s);
    e = __builtin_amdgcn_readfirstlane(e);
    float nd = dinv[w];
    float2 acc = make_float2(0.0f, 0.0f);
    for (int j = s; j < e; ++j) {
        int nb = eidx[j];
        float wgt = nd * dinv[nb];
        float2 v = ldb2(x016 + (size_t)nb * HD, lane);
        acc.x = fmaf(v.x, wgt, acc.x);
        acc.y = fmaf(v.y, wgt, acc.y);
    }
    stb2(x116 + (size_t)w * HD, lane, acc);
}

__global__ void k_gather2(const int* __restrict__ rs, const int* __restrict__ eidx,
                          const float* __restrict__ dinv,
                          const bf16* __restrict__ x016, const bf16* __restrict__ x116,
                          bf16* __restrict__ xf16) {
    int w    = (blockIdx.x * blockDim.x + threadIdx.x) >> 6;
    int lane = threadIdx.x & 63;
    if (w >= N_TOT) return;
    int s = (w == 0) ? 0 : rs[w - 1];
    int e = rs[w];
    s = __builtin_amdgcn_readfirstlane(s);
    e = __builtin_amdgcn_readfirstlane(e);
    float nd = dinv[w];
    float2 acc = make_float2(0.0f, 0.0f);
    for (int j = s; j < e; ++j) {
        int nb = eidx[j];
        float wgt = nd * dinv[nb];
        float2 v = ldb2(x116 + (size_t)nb * HD, lane);
        acc.x = fmaf(v.x, wgt, acc.x);
        acc.y = fmaf(v.y, wgt, acc.y);
    }
    float2 a = ldb2(x016 + (size_t)w * HD, lane);
    float2 b = ldb2(x116 + (size_t)w * HD, lane);
    acc.x = (acc.x + a.x + b.x) * (1.0f / 3.0f);
    acc.y = (acc.y + a.y + b.y) * (1.0f / 3.0f);
    stb2(xf16 + (size_t)w * HD, lane, acc);
}

__global__ void k_gather_bb(const int* __restrict__ rs, const int* __restrict__ eidx,
                            const bf16* __restrict__ h16, float* __restrict__ agg) {
    int w    = (blockIdx.x * blockDim.x + threadIdx.x) >> 6;
    int lane = threadIdx.x & 63;
    if (w >= B_N) return;
    int s = (w == 0) ? 0 : rs[w - 1];
    int e = rs[w];
    s = __builtin_amdgcn_readfirstlane(s);
    e = __builtin_amdgcn_readfirstlane(e);
    float2 acc = make_float2(0.0f, 0.0f);
    for (int j = s; j < e; ++j) {
        int nb = eidx[j];
        float2 v = ldb2(h16 + (size_t)nb * HD, lane);
        acc.x += v.x;
        acc.y += v.y;
    }
    float inv = 1.0f / fmaxf((float)(e - s), 1.0f);
    acc.x *= inv;
    acc.y *= inv;
    ((float2*)(agg + (size_t)w * HD))[lane] = acc;
}

// hout = relu(agg@Wl + bl + h@Wr); 16 rows/block (2 loads : 32 FMA per k).
// In-place safe: rows staged in LDS behind barrier; blocks never share rows.
__global__ __launch_bounds__(128)
void k_glayer(const float* __restrict__ agg, const float* __restrict__ h,
              const float* __restrict__ Wl, const float* __restrict__ bl,
              const float* __restrict__ Wr,
              float* outf, bf16* out16) {
    __shared__ float sa[16][HD];
    __shared__ float sh[16][HD];
    const int c  = threadIdx.x;
    const int r0 = blockIdx.x * 16;
#pragma unroll
    for (int i = 0; i < 16; i++) {
        int r = r0 + i;
        sa[i][c] = (r < B_N) ? agg[(size_t)r * HD + c] : 0.0f;
        sh[i][c] = (r < B_N) ? h[(size_t)r * HD + c] : 0.0f;
    }
    __syncthreads();
    float acc[16];
#pragma unroll
    for (int i = 0; i < 16; i++) acc[i] = 0.0f;
    for (int k = 0; k < HD; k++) {
        float wl = Wl[k * HD + c];
        float wr = Wr[k * HD + c];
#pragma unroll
        for (int i = 0; i < 16; i++) {
            acc[i] = fmaf(sa[i][k], wl, acc[i]);
            acc[i] = fmaf(sh[i][k], wr, acc[i]);
        }
    }
    float bv = bl[c];
#pragma unroll
    for (int i = 0; i < 16; i++) {
        int r = r0 + i;
        if (r < B_N) {
            float v = fmaxf(acc[i] + bv, 0.0f);
            if (outf)  outf[(size_t)r * HD + c] = v;
            if (out16) out16[(size_t)r * HD + c] = __float2bfloat16(v);
        }
    }
}

// attention fusion head, 8 rows per 128-thread block (2 waves)
__global__ __launch_bounds__(128)
void k_fuse(const bf16* __restrict__ collab16, const bf16* __restrict__ content16,
            const float* __restrict__ Wf1, const float* __restrict__ bf1v,
            const float* __restrict__ Wf2, const float* __restrict__ bf2v,
            bf16* __restrict__ fused16) {
    const int R = 8;
    __shared__ float sc[R][HD];
    __shared__ float sh[R][HD];
    __shared__ float part[2][R][2];
    __shared__ float attn[R][2];
    const int c  = threadIdx.x;
    const int r0 = blockIdx.x * R;
#pragma unroll
    for (int i = 0; i < R; i++) {
        int r = r0 + i;
        sc[i][c] = (r < B_N) ? b2f(collab16[(size_t)r * HD + c]) : 0.0f;
        sh[i][c] = (r < B_N) ? b2f(content16[(size_t)r * HD + c]) : 0.0f;
    }
    __syncthreads();
    float t[R];
#pragma unroll
    for (int i = 0; i < R; i++) t[i] = 0.0f;
    for (int k = 0; k < HD; k++) {
        float w = Wf1[k * HD + c];
#pragma unroll
        for (int i = 0; i < R; i++) t[i] = fmaf(sc[i][k], w, t[i]);
    }
    for (int k = 0; k < HD; k++) {
        float w = Wf1[(size_t)(HD + k) * HD + c];
#pragma unroll
        for (int i = 0; i < R; i++) t[i] = fmaf(sh[i][k], w, t[i]);
    }
    float b1  = bf1v[c];
    float w20 = Wf2[c * 2 + 0];
    float w21 = Wf2[c * 2 + 1];
    float p0[R], p1[R];
#pragma unroll
    for (int i = 0; i < R; i++) {
        float tv = fmaxf(t[i] + b1, 0.0f);
        p0[i] = tv * w20;
        p1[i] = tv * w21;
    }
#pragma unroll
    for (int i = 0; i < R; i++) {
        for (int off = 32; off > 0; off >>= 1) {
            p0[i] += __shfl_down(p0[i], off, 64);
            p1[i] += __shfl_down(p1[i], off, 64);
        }
    }
    int wv   = threadIdx.x >> 6;
    int lane = threadIdx.x & 63;
    if (lane == 0) {
#pragma unroll
        for (int i = 0; i < R; i++) { part[wv][i][0] = p0[i]; part[wv][i][1] = p1[i]; }
    }
    __syncthreads();
    if (threadIdx.x < R) {
        int i = threadIdx.x;
        float s0 = part[0][i][0] + part[1][i][0] + bf2v[0];
        float s1 = part[0][i][1] + part[1][i][1] + bf2v[1];
        float m  = fmaxf(s0, s1);
        float e0 = expf(s0 - m), e1 = expf(s1 - m);
        float inv = 1.0f / (e0 + e1);
        attn[i][0] = e0 * inv;
        attn[i][1] = e1 * inv;
    }
    __syncthreads();
#pragma unroll
    for (int i = 0; i < R; i++) {
        int r = r0 + i;
        if (r < B_N) {
            float v = attn[i][0] * sc[i][c] + attn[i][1] * sh[i][c];
            fused16[(size_t)r * HD + c] = __float2bfloat16(v);
        }
    }
}

// one wave per prediction: dot(uemb16[pu], fused16[pb]); f32 out
__global__ void k_score(const int* __restrict__ pu, const int* __restrict__ pb,
                        const bf16* __restrict__ uemb16, const bf16* __restrict__ fused16,
                        float* __restrict__ out) {
    int wid  = (blockIdx.x * blockDim.x + threadIdx.x) >> 6;
    int lane = threadIdx.x & 63;
    if (wid >= NP) return;
    int u = pu[wid];
    int b = pb[wid];
    float2 a = ldb2(uemb16 + (size_t)u * HD, lane);
    float2 f = ldb2(fused16 + (size_t)b * HD, lane);
    float s = a.x * f.x + a.y * f.y;
    for (int off = 32; off > 0; off >>= 1) s += __shfl_down(s, off, 64);
    if (lane == 0) out[wid] = s;
}

extern "C" void kernel_launch(void* const* d_in, const int* in_sizes, int n_in,
                              void* d_out, int out_size, void* d_ws, size_t ws_size,
                              hipStream_t stream) {
    const float* user_x = (const float*)d_in[0];
    const float* book_x = (const float*)d_in[1];
    const int*   ub_src = (const int*)d_in[2];
    const int*   ub_dst = (const int*)d_in[3];
    const int*   bb_src = (const int*)d_in[4];
    const int*   bb_dst = (const int*)d_in[5];
    const int*   pred_u = (const int*)d_in[6];
    const int*   pred_b = (const int*)d_in[7];
    const float* Wu   = (const float*)d_in[8];
    const float* bu   = (const float*)d_in[9];
    const float* Wub  = (const float*)d_in[10];
    const float* bub  = (const float*)d_in[11];
    const float* Wbb  = (const float*)d_in[12];
    const float* bbb  = (const float*)d_in[13];
    const float* Wl1  = (const float*)d_in[14];
    const float* bl1  = (const float*)d_in[15];
    const float* Wr1  = (const float*)d_in[16];
    const float* Wl2  = (const float*)d_in[17];
    const float* bl2  = (const float*)d_in[18];
    const float* Wr2  = (const float*)d_in[19];
    const float* Wf1  = (const float*)d_in[20];
    const float* bf1v = (const float*)d_in[21];
    const float* Wf2  = (const float*)d_in[22];
    const float* bf2v = (const float*)d_in[23];
    float* out = (float*)d_out;

    // ---- workspace layout: 30.96M words = 123.84 MB (same as passing R9) ----
    float* ws = (float*)d_ws;
    const size_t need = 30960000ull * sizeof(float);
    if (ws_size < need) return;

    float* dinv    = ws;
    int*   cnt_ub  = (int*)(ws + 150000);
    int*   rs_ub   = (int*)(ws + 300000);
    int*   cnt_bb  = (int*)(ws + 450000);
    int*   rs_bb   = (int*)(ws + 500000);
    int*   bsum    = (int*)(ws + 550000);
    int*   eidx    = (int*)(ws + 560000);
    bf16*  X016    = (bf16*)(ws + 2160000);      // [2160000, 11760000)
    bf16*  X1_16   = (bf16*)(ws + 11760000);     // [11760000, 21360000)
    bf16*  XF16    = (bf16*)(ws + 21360000);     // [21360000, 30960000)
    float* hf        = ws + 2160000;             // [2160000, 8560000)
    bf16*  h16       = (bf16*)(ws + 8560000);    // [8560000, 11760000)
    float* aggf      = ws + 11760000;            // [11760000, 18160000)
    bf16*  content16 = h16;
    bf16*  fused16   = (bf16*)(ws + 11760000);
    bf16*  uemb16    = XF16;
    bf16*  collab16  = XF16 + (size_t)U_N * HD;

    hipMemsetAsync(ws + 150000, 0, 350000 * sizeof(float), stream);

    // x0 -> X016 (bf16)
    k_init_gemm<DU><<<(U_N + 15) / 16, 128, 0, stream>>>(
        user_x, Wu, bu, (float*)nullptr, X016, U_N);
    k_init_gemm<DB><<<(B_N + 15) / 16, 128, 0, stream>>>(
        book_x, Wub, bub, (float*)nullptr, X016 + (size_t)U_N * HD, B_N);

    // ---- CSR build (ub graph, bidirectional) ----
    k_cnt_ub<<<(NE_UB + 255) / 256, 256, 0, stream>>>(ub_src, ub_dst, cnt_ub);
    k_cnt_bb<<<(NE_BB + 255) / 256, 256, 0, stream>>>(bb_dst, cnt_bb);
    k_dinv<<<(N_TOT + 255) / 256, 256, 0, stream>>>(cnt_ub, dinv);
    {
        int nb = (N_TOT + 1023) / 1024;
        k_scan1<<<nb, 256, 0, stream>>>(cnt_ub, rs_ub, bsum, N_TOT);
        k_scan2<<<1, 256, 0, stream>>>(bsum, nb);
        k_scan3<<<(N_TOT + 255) / 256, 256, 0, stream>>>(rs_ub, bsum, N_TOT);
    }
    k_fill_ub<<<(NE_UB + 255) / 256, 256, 0, stream>>>(ub_src, ub_dst, rs_ub, eidx);

    // ---- LightGCN propagation ----
    k_gather1<<<(N_TOT + 3) / 4, 256, 0, stream>>>(rs_ub, eidx, dinv, X016, X1_16);
    k_gather2<<<(N_TOT + 3) / 4, 256, 0, stream>>>(rs_ub, eidx, dinv, X016, X1_16, XF16);

    // ---- CSR build (bb graph) ----
    {
        int nb = (B_N + 1023) / 1024;
        k_scan1<<<nb, 256, 0, stream>>>(cnt_bb, rs_bb, bsum, B_N);
        k_scan2<<<1, 256, 0, stream>>>(bsum, nb);
        k_scan3<<<(B_N + 255) / 256, 256, 0, stream>>>(rs_bb, bsum, B_N);
    }
    k_fill_bb<<<(NE_BB + 255) / 256, 256, 0, stream>>>(bb_src, bb_dst, rs_bb, eidx);

    // ---- content network ----
    k_init_gemm<DB><<<(B_N + 15) / 16, 128, 0, stream>>>(book_x, Wbb, bbb, hf, h16, B_N);
    k_gather_bb<<<(B_N + 3) / 4, 256, 0, stream>>>(rs_bb, eidx, h16, aggf);
    k_glayer<<<(B_N + 15) / 16, 128, 0, stream>>>(aggf, hf, Wl1, bl1, Wr1, hf, h16);
    k_gather_bb<<<(B_N + 3) / 4, 256, 0, stream>>>(rs_bb, eidx, h16, aggf);
    k_glayer<<<(B_N + 15) / 16, 128, 0, stream>>>(aggf, hf, Wl2, bl2, Wr2,
                                                  (float*)nullptr, content16);

    // ---- fusion + scores ----
    k_fuse<<<(B_N + 7) / 8, 128, 0, stream>>>(collab16, content16,
                                              Wf1, bf1v, Wf2, bf2v, fused16);
    k_score<<<NP / 4, 256, 0, stream>>>(pred_u, pred_b, uemb16, fused16, out);
}